// Round 3
// baseline (376.469 us; speedup 1.0000x reference)
//
#include <hip/hip_runtime.h>
#include <stdint.h>

typedef unsigned short u16;
typedef __attribute__((ext_vector_type(8))) short bf16x8;
typedef __attribute__((ext_vector_type(4))) float f32x4;

#define LOG2E 1.44269504088896340736f

__device__ __forceinline__ float bf2f(u16 u) {
  union { uint32_t u; float f; } v; v.u = ((uint32_t)u) << 16; return v.f;
}
__device__ __forceinline__ u16 f2bf(float f) {
  union { float f; uint32_t u; } v; v.f = f;
  uint32_t r = v.u + 0x7fffu + ((v.u >> 16) & 1u);
  return (u16)(r >> 16);
}

// async global->LDS, 16B per lane; lds ptr must be wave-uniform base (HW adds lane*16)
__device__ __forceinline__ void gl_lds16(const u16* g, u16* l) {
  __builtin_amdgcn_global_load_lds((const __attribute__((address_space(1))) void*)g,
                                   (__attribute__((address_space(3))) void*)l, 16, 0, 0);
}

// ---------------- x: fp32 -> bf16 ----------------
__global__ __launch_bounds__(256) void k_cvt_x(const float* __restrict__ x,
                                               u16* __restrict__ xb) {
  const int i = blockIdx.x * 256 + threadIdx.x;
  float4 v = ((const float4*)x)[i];
  ushort4 o;
  o.x = f2bf(v.x); o.y = f2bf(v.y); o.z = f2bf(v.z); o.w = f2bf(v.w);
  ((ushort4*)xb)[i] = o;
}

// ---------------- transpose fp32 -> bf16 (64x64 tile via LDS) ----------------
__device__ __forceinline__ void transpose64f(const float* src, int sstride,
                                             u16* dst, int dstride,
                                             float scale, u16* tile /*64*80*/) {
  const int tid = threadIdx.x;
  const int row = tid >> 3, seg = tid & 7;
#pragma unroll
  for (int p = 0; p < 2; ++p) {
    int rr = p * 32 + row;
    float4 a = *(const float4*)(src + rr * sstride + seg * 8);
    float4 b = *(const float4*)(src + rr * sstride + seg * 8 + 4);
    tile[(seg * 8 + 0) * 80 + rr] = f2bf(a.x * scale);
    tile[(seg * 8 + 1) * 80 + rr] = f2bf(a.y * scale);
    tile[(seg * 8 + 2) * 80 + rr] = f2bf(a.z * scale);
    tile[(seg * 8 + 3) * 80 + rr] = f2bf(a.w * scale);
    tile[(seg * 8 + 4) * 80 + rr] = f2bf(b.x * scale);
    tile[(seg * 8 + 5) * 80 + rr] = f2bf(b.y * scale);
    tile[(seg * 8 + 6) * 80 + rr] = f2bf(b.z * scale);
    tile[(seg * 8 + 7) * 80 + rr] = f2bf(b.w * scale);
  }
  __syncthreads();
#pragma unroll
  for (int p = 0; p < 2; ++p) {
    int rr = p * 32 + row;
    *(uint4*)(dst + rr * dstride + seg * 8) = *(uint4*)(tile + rr * 80 + seg * 8);
  }
}

// ---------------- transpose bf16 -> bf16 (for V) ----------------
__device__ __forceinline__ void transpose64(const u16* src, int sstride,
                                            u16* dst, int dstride, u16* tile) {
  const int tid = threadIdx.x;
  const int row = tid >> 3, seg = tid & 7;
  union { uint4 u; u16 s[8]; } tv;
#pragma unroll
  for (int p = 0; p < 2; ++p) {
    int rr = p * 32 + row;
    tv.u = *(const uint4*)(src + rr * sstride + seg * 8);
#pragma unroll
    for (int j = 0; j < 8; ++j)
      tile[(seg * 8 + j) * 80 + rr] = tv.s[j];
  }
  __syncthreads();
#pragma unroll
  for (int p = 0; p < 2; ++p) {
    int rr = p * 32 + row;
    *(uint4*)(dst + rr * dstride + seg * 8) = *(uint4*)(tile + rr * 80 + seg * 8);
  }
}

// Wq|Wk|Wv (each 256x2048 fp32, row-major in->out) -> Wt (6144x256 bf16), q/k scaled 0.25
__global__ __launch_bounds__(256) void k_transpose_wqkv(const float* __restrict__ Wq,
                                                        const float* __restrict__ Wk,
                                                        const float* __restrict__ Wv,
                                                        u16* __restrict__ Wt) {
  __shared__ u16 tile[64 * 80];
  const int o0 = blockIdx.x * 64, i0 = blockIdx.y * 64;
  const float* src; float scale = 0.25f; int oc0 = o0;
  if (o0 < 2048)      { src = Wq; }
  else if (o0 < 4096) { src = Wk; oc0 = o0 - 2048; }
  else                { src = Wv; oc0 = o0 - 4096; scale = 1.0f; }
  transpose64f(src + i0 * 2048 + oc0, 2048, Wt + o0 * 256 + i0, 256, scale, tile);
}

// Wu (2048x256 fp32) -> Wut (256x2048 bf16)
__global__ __launch_bounds__(256) void k_transpose_wu(const float* __restrict__ Wu,
                                                      u16* __restrict__ Wut) {
  __shared__ u16 tile[64 * 80];
  const int c0 = blockIdx.x * 64, r0 = blockIdx.y * 64;
  transpose64f(Wu + r0 * 256 + c0, 256, Wut + c0 * 2048 + r0, 2048, 1.0f, tile);
}

// V slice of qkv (b,t,h,d) -> vt (b,h,d,t), bf16
__global__ __launch_bounds__(256) void k_transpose_v(const u16* __restrict__ qkv,
                                                     u16* __restrict__ vt) {
  __shared__ u16 tile[64 * 80];
  const int bh = blockIdx.z;
  const int b = bh >> 3, h = bh & 7;
  const int t0 = blockIdx.y * 64, d0 = blockIdx.x * 64;
  const u16* src = qkv + ((size_t)(b * 1024 + t0)) * 6144 + 4096 + h * 256 + d0;
  u16* dst = vt + ((size_t)(bh * 256 + d0)) * 1024 + t0;
  transpose64(src, 6144, dst, 1024, tile);
}

// ---------------- QKV projection GEMM ----------------
// A = xb (8192x256 bf16), Bt = Wt (6144x256), C = qkv (8192x6144 bf16)
__global__ __launch_bounds__(256) void k_gemm_qkv(const u16* __restrict__ A,
                                                  const u16* __restrict__ Bt,
                                                  u16* __restrict__ C) {
  __shared__ u16 As[128 * 32];
  __shared__ u16 Bs[128 * 32];
  const int m0 = blockIdx.y * 128, n0 = blockIdx.x * 128;
  const int tid = threadIdx.x, w = tid >> 6, lane = tid & 63;
  const int q = lane >> 4, r = lane & 15;
  const int wm = (w >> 1) * 64, wn = (w & 1) * 64;
  const int bo0 = w * 2048 + lane * 16;          // byte offset, issue 0
  const int row0 = bo0 >> 6, col0 = (bo0 & 63) >> 1;
  const int bo1 = bo0 + 1024;
  const int row1 = bo1 >> 6, col1 = (bo1 & 63) >> 1;
  f32x4 acc[4][4] = {};
  for (int kt = 0; kt < 256; kt += 32) {
    __syncthreads();
    gl_lds16(A + (m0 + row0) * 256 + kt + col0, As + w * 1024);
    gl_lds16(A + (m0 + row1) * 256 + kt + col1, As + w * 1024 + 512);
    gl_lds16(Bt + (n0 + row0) * 256 + kt + col0, Bs + w * 1024);
    gl_lds16(Bt + (n0 + row1) * 256 + kt + col1, Bs + w * 1024 + 512);
    __syncthreads();
    bf16x8 af[4], bf[4];
#pragma unroll
    for (int mb = 0; mb < 4; ++mb) af[mb] = *(const bf16x8*)(As + (wm + mb * 16 + r) * 32 + q * 8);
#pragma unroll
    for (int nb = 0; nb < 4; ++nb) bf[nb] = *(const bf16x8*)(Bs + (wn + nb * 16 + r) * 32 + q * 8);
#pragma unroll
    for (int mb = 0; mb < 4; ++mb)
#pragma unroll
      for (int nb = 0; nb < 4; ++nb)
        acc[mb][nb] = __builtin_amdgcn_mfma_f32_16x16x32_bf16(af[mb], bf[nb], acc[mb][nb], 0, 0, 0);
  }
#pragma unroll
  for (int mb = 0; mb < 4; ++mb)
#pragma unroll
    for (int nb = 0; nb < 4; ++nb) {
      const int nn = n0 + wn + nb * 16 + r;
#pragma unroll
      for (int reg = 0; reg < 4; ++reg) {
        const int mm = m0 + wm + mb * 16 + q * 4 + reg;
        C[(size_t)mm * 6144 + nn] = f2bf(acc[mb][nb][reg]);
      }
    }
}

// ---------------- fused flash attention ----------------
// qkv: (8192 x 6144) [Q|K|V], Q/K pre-scaled by 1/4 via weights. vt: (b,h,d=256,t=1024).
// att out: (8192 x 2048) bf16 = (b,t,h*256+d)
__global__ __launch_bounds__(256) void k_attn(const u16* __restrict__ qkv,
                                              const u16* __restrict__ vt,
                                              u16* __restrict__ att) {
  __shared__ u16 smem[19200];     // Ks[32*264] | Vs[256*32] | Ps[4][16*40]
  u16* Ks = smem;                  // pitch 264 (pad breaks 512B-stride conflicts)
  u16* Vs = smem + 8448;           // [d][s] pitch 32
  const int blk = blockIdx.x;
  const int qt = blk & 15, h = (blk >> 4) & 7, b = blk >> 7;
  const int tid = threadIdx.x, w = tid >> 6, lane = tid & 63;
  const int q = lane >> 4, r = lane & 15;
  const int t0 = qt * 64 + w * 16;
  u16* Pw = smem + 16640 + w * 640;  // [16][40]

  // Q fragments straight from global (one-time)
  const u16* Qg = qkv + ((size_t)(b * 1024 + t0 + r)) * 6144 + h * 256;
  bf16x8 qf[8];
#pragma unroll
  for (int kc = 0; kc < 8; ++kc) qf[kc] = *(const bf16x8*)(Qg + kc * 32 + q * 8);

  float m_i[4], l_i[4], al[4];
  f32x4 o[16] = {};
#pragma unroll
  for (int reg = 0; reg < 4; ++reg) { m_i[reg] = -3.0e38f; l_i[reg] = 0.0f; }

  const u16* Kg = qkv + (size_t)b * 1024 * 6144 + 2048 + h * 256;
  const u16* Vg = vt + (size_t)(b * 8 + h) * 256 * 1024;

  for (int sc = 0; sc < 1024; sc += 32) {
    __syncthreads();  // everyone done reading prev chunk
    // stage K chunk: 32 keys x 256 d, padded pitch 264
#pragma unroll
    for (int p = 0; p < 4; ++p) {
      int idx = (p * 256 + tid) * 8;
      int row = idx >> 8, col = idx & 255;
      uint4 v = *(const uint4*)(Kg + (size_t)(sc + row) * 6144 + col);
      *(uint4*)(Ks + row * 264 + col) = v;
    }
    // stage V^T chunk: 256 d-rows x 32 keys
#pragma unroll
    for (int p = 0; p < 4; ++p) {
      uint4 v = *(const uint4*)(Vg + (size_t)tid * 1024 + sc + p * 8);
      *(uint4*)(Vs + tid * 32 + p * 8) = v;
    }
    __syncthreads();

    // S = Q K^T  (two 16x16 key blocks)
    f32x4 sA = {}, sB = {};
#pragma unroll
    for (int kc = 0; kc < 8; ++kc) {
      bf16x8 k0 = *(const bf16x8*)(Ks + r * 264 + kc * 32 + q * 8);
      bf16x8 k1 = *(const bf16x8*)(Ks + (16 + r) * 264 + kc * 32 + q * 8);
      sA = __builtin_amdgcn_mfma_f32_16x16x32_bf16(qf[kc], k0, sA, 0, 0, 0);
      sB = __builtin_amdgcn_mfma_f32_16x16x32_bf16(qf[kc], k1, sB, 0, 0, 0);
    }

    // online softmax; row = q*4+reg, col(key) = r / 16+r
#pragma unroll
    for (int reg = 0; reg < 4; ++reg) {
      float v = fmaxf(sA[reg], sB[reg]);
      v = fmaxf(v, __shfl_xor(v, 1)); v = fmaxf(v, __shfl_xor(v, 2));
      v = fmaxf(v, __shfl_xor(v, 4)); v = fmaxf(v, __shfl_xor(v, 8));
      float mn = fmaxf(m_i[reg], v);
      float a = exp2f((m_i[reg] - mn) * LOG2E);
      float p0 = exp2f((sA[reg] - mn) * LOG2E);
      float p1 = exp2f((sB[reg] - mn) * LOG2E);
      float rs = p0 + p1;
      rs += __shfl_xor(rs, 1); rs += __shfl_xor(rs, 2);
      rs += __shfl_xor(rs, 4); rs += __shfl_xor(rs, 8);
      l_i[reg] = l_i[reg] * a + rs;
      m_i[reg] = mn; al[reg] = a;
      Pw[(q * 4 + reg) * 40 + r] = f2bf(p0);
      Pw[(q * 4 + reg) * 40 + 16 + r] = f2bf(p1);
    }
#pragma unroll
    for (int db = 0; db < 16; ++db) {
      f32x4 t = o[db];
#pragma unroll
      for (int reg = 0; reg < 4; ++reg) t[reg] *= al[reg];
      o[db] = t;
    }
    asm volatile("s_waitcnt lgkmcnt(0)" ::: "memory");  // P writes visible to own wave
    bf16x8 pf = *(const bf16x8*)(Pw + r * 40 + q * 8);  // A-operand layout
#pragma unroll
    for (int db = 0; db < 16; ++db) {
      bf16x8 vf = *(const bf16x8*)(Vs + (db * 16 + r) * 32 + q * 8);
      o[db] = __builtin_amdgcn_mfma_f32_16x16x32_bf16(pf, vf, o[db], 0, 0, 0);
    }
  }

  // normalize
  float rl[4];
#pragma unroll
  for (int reg = 0; reg < 4; ++reg) rl[reg] = 1.0f / l_i[reg];
#pragma unroll
  for (int db = 0; db < 16; ++db) {
    f32x4 t = o[db];
#pragma unroll
    for (int reg = 0; reg < 4; ++reg) t[reg] *= rl[reg];
    o[db] = t;
  }

  // stage O through LDS (per-wave 16x264 region) for coalesced 16B stores
  __syncthreads();  // all waves done with Ks/Vs
  u16* Os = smem + w * 4224;
#pragma unroll
  for (int db = 0; db < 16; ++db)
#pragma unroll
    for (int reg = 0; reg < 4; ++reg)
      Os[(q * 4 + reg) * 264 + db * 16 + r] = f2bf(o[db][reg]);
  asm volatile("s_waitcnt lgkmcnt(0)" ::: "memory");
  u16* Ag = att + ((size_t)(b * 1024 + t0)) * 2048 + h * 256;
#pragma unroll
  for (int p = 0; p < 8; ++p) {
    int idx = (p * 64 + lane) * 8;
    int row = idx >> 8, col = idx & 255;
    *(uint4*)(Ag + (size_t)row * 2048 + col) = *(uint4*)(Os + row * 264 + col);
  }
}

// ---------------- unify GEMM + bias ----------------
// A = att (8192x2048), Bt = Wut (256x2048), bu fp32, out FP32 (8192x256)
__global__ __launch_bounds__(256) void k_gemm_out(const u16* __restrict__ A,
                                                  const u16* __restrict__ Bt,
                                                  const float* __restrict__ bu,
                                                  float* __restrict__ C) {
  __shared__ u16 As[128 * 32];
  __shared__ u16 Bs[64 * 32];
  const int m0 = blockIdx.y * 128, n0 = blockIdx.x * 64;
  const int tid = threadIdx.x, w = tid >> 6, lane = tid & 63;
  const int q = lane >> 4, r = lane & 15;
  const int wm = (w >> 1) * 64, wn = (w & 1) * 32;
  const int boA0 = w * 2048 + lane * 16;
  const int rA0 = boA0 >> 6, cA0 = (boA0 & 63) >> 1;
  const int boA1 = boA0 + 1024;
  const int rA1 = boA1 >> 6, cA1 = (boA1 & 63) >> 1;
  const int boB = w * 1024 + lane * 16;
  const int rB = boB >> 6, cB = (boB & 63) >> 1;
  f32x4 acc[4][2] = {};
  for (int kt = 0; kt < 2048; kt += 32) {
    __syncthreads();
    gl_lds16(A + (size_t)(m0 + rA0) * 2048 + kt + cA0, As + w * 1024);
    gl_lds16(A + (size_t)(m0 + rA1) * 2048 + kt + cA1, As + w * 1024 + 512);
    gl_lds16(Bt + (size_t)(n0 + rB) * 2048 + kt + cB, Bs + w * 512);
    __syncthreads();
    bf16x8 af[4], bf[2];
#pragma unroll
    for (int mb = 0; mb < 4; ++mb) af[mb] = *(const bf16x8*)(As + (wm + mb * 16 + r) * 32 + q * 8);
#pragma unroll
    for (int nb = 0; nb < 2; ++nb) bf[nb] = *(const bf16x8*)(Bs + (wn + nb * 16 + r) * 32 + q * 8);
#pragma unroll
    for (int mb = 0; mb < 4; ++mb)
#pragma unroll
      for (int nb = 0; nb < 2; ++nb)
        acc[mb][nb] = __builtin_amdgcn_mfma_f32_16x16x32_bf16(af[mb], bf[nb], acc[mb][nb], 0, 0, 0);
  }
  float bias[2];
#pragma unroll
  for (int nb = 0; nb < 2; ++nb) bias[nb] = bu[n0 + wn + nb * 16 + r];
#pragma unroll
  for (int mb = 0; mb < 4; ++mb)
#pragma unroll
    for (int nb = 0; nb < 2; ++nb) {
      const int nn = n0 + wn + nb * 16 + r;
#pragma unroll
      for (int reg = 0; reg < 4; ++reg) {
        const int mm = m0 + wm + mb * 16 + q * 4 + reg;
        C[(size_t)mm * 256 + nn] = acc[mb][nb][reg] + bias[nb];
      }
    }
}

extern "C" void kernel_launch(void* const* d_in, const int* in_sizes, int n_in,
                              void* d_out, int out_size, void* d_ws, size_t ws_size,
                              hipStream_t stream) {
  const float* x  = (const float*)d_in[0];   // (8192, 256) fp32
  const float* Wq = (const float*)d_in[1];   // (256, 2048) fp32
  const float* Wk = (const float*)d_in[2];
  const float* Wv = (const float*)d_in[3];
  const float* Wu = (const float*)d_in[4];   // (2048, 256) fp32
  const float* bu = (const float*)d_in[5];   // (256,) fp32
  float* outp = (float*)d_out;               // (8192, 256) fp32

  char* ws = (char*)d_ws;
  u16* qkv   = (u16*)(ws);                          // 8192*6144*2  = 100663296
  u16* vt    = (u16*)(ws + 100663296);              // 64*256*1024*2 = 33554432
  u16* attb  = (u16*)(ws + 134217728);              // 8192*2048*2  = 33554432
  u16* wqkvt = (u16*)(ws + 167772160);              // 6144*256*2   = 3145728
  u16* wut   = (u16*)(ws + 170917888);              // 256*2048*2   = 1048576
  u16* xb    = (u16*)(ws + 171966464);              // 8192*256*2   = 4194304
  (void)in_sizes; (void)n_in; (void)out_size; (void)ws_size;

  dim3 blk(256);
  k_cvt_x<<<dim3(2048), blk, 0, stream>>>(x, xb);
  k_transpose_wqkv<<<dim3(96, 4), blk, 0, stream>>>(Wq, Wk, Wv, wqkvt);
  k_transpose_wu<<<dim3(4, 32), blk, 0, stream>>>(Wu, wut);
  k_gemm_qkv<<<dim3(48, 64), blk, 0, stream>>>(xb, wqkvt, qkv);
  k_transpose_v<<<dim3(4, 16, 64), blk, 0, stream>>>(qkv, vt);
  k_attn<<<dim3(1024), blk, 0, stream>>>(qkv, vt, attb);
  k_gemm_out<<<dim3(4, 64), blk, 0, stream>>>(attb, wut, bu, outp);
}

// Round 4
// 323.090 us; speedup vs baseline: 1.1652x; 1.1652x over previous
//
#include <hip/hip_runtime.h>
#include <stdint.h>

typedef unsigned short u16;
typedef __attribute__((ext_vector_type(8))) short bf16x8;
typedef __attribute__((ext_vector_type(4))) float f32x4;

#define LOG2E 1.44269504088896340736f

__device__ __forceinline__ float bf2f(u16 u) {
  union { uint32_t u; float f; } v; v.u = ((uint32_t)u) << 16; return v.f;
}
__device__ __forceinline__ u16 f2bf(float f) {
  union { float f; uint32_t u; } v; v.f = f;
  uint32_t r = v.u + 0x7fffu + ((v.u >> 16) & 1u);
  return (u16)(r >> 16);
}

// async global->LDS, 16B per lane; lds ptr must be wave-uniform base (HW adds lane*16)
__device__ __forceinline__ void gl_lds16(const u16* g, u16* l) {
  __builtin_amdgcn_global_load_lds((const __attribute__((address_space(1))) void*)g,
                                   (__attribute__((address_space(3))) void*)l, 16, 0, 0);
}

// ---------------- x: fp32 -> bf16 ----------------
__global__ __launch_bounds__(256) void k_cvt_x(const float* __restrict__ x,
                                               u16* __restrict__ xb) {
  const int i = blockIdx.x * 256 + threadIdx.x;
  float4 v = ((const float4*)x)[i];
  ushort4 o;
  o.x = f2bf(v.x); o.y = f2bf(v.y); o.z = f2bf(v.z); o.w = f2bf(v.w);
  ((ushort4*)xb)[i] = o;
}

// ---------------- transpose fp32 -> bf16 (64x64 tile via LDS, XOR-swizzled) ----------------
// element (c, r) stored at tile[c*80 + (r ^ (((c>>3)&7)*8))] -> conflict-free both phases
__device__ __forceinline__ void transpose64f(const float* src, int sstride,
                                             u16* dst, int dstride,
                                             float scale, u16* tile /*64*80*/) {
  const int tid = threadIdx.x;
  const int row = tid >> 3, seg = tid & 7;
#pragma unroll
  for (int p = 0; p < 2; ++p) {
    int rr = p * 32 + row;
    int rw = rr ^ (seg * 8);
    float4 a = *(const float4*)(src + rr * sstride + seg * 8);
    float4 b = *(const float4*)(src + rr * sstride + seg * 8 + 4);
    tile[(seg * 8 + 0) * 80 + rw] = f2bf(a.x * scale);
    tile[(seg * 8 + 1) * 80 + rw] = f2bf(a.y * scale);
    tile[(seg * 8 + 2) * 80 + rw] = f2bf(a.z * scale);
    tile[(seg * 8 + 3) * 80 + rw] = f2bf(a.w * scale);
    tile[(seg * 8 + 4) * 80 + rw] = f2bf(b.x * scale);
    tile[(seg * 8 + 5) * 80 + rw] = f2bf(b.y * scale);
    tile[(seg * 8 + 6) * 80 + rw] = f2bf(b.z * scale);
    tile[(seg * 8 + 7) * 80 + rw] = f2bf(b.w * scale);
  }
  __syncthreads();
#pragma unroll
  for (int p = 0; p < 2; ++p) {
    int rr = p * 32 + row;
    int sw = (seg ^ ((rr >> 3) & 7)) * 8;
    *(uint4*)(dst + rr * dstride + seg * 8) = *(uint4*)(tile + rr * 80 + sw);
  }
}

// ---------------- transpose bf16 -> bf16 (for V), XOR-swizzled ----------------
__device__ __forceinline__ void transpose64(const u16* src, int sstride,
                                            u16* dst, int dstride, u16* tile) {
  const int tid = threadIdx.x;
  const int row = tid >> 3, seg = tid & 7;
  union { uint4 u; u16 s[8]; } tv;
#pragma unroll
  for (int p = 0; p < 2; ++p) {
    int rr = p * 32 + row;
    int rw = rr ^ (seg * 8);
    tv.u = *(const uint4*)(src + rr * sstride + seg * 8);
#pragma unroll
    for (int j = 0; j < 8; ++j)
      tile[(seg * 8 + j) * 80 + rw] = tv.s[j];
  }
  __syncthreads();
#pragma unroll
  for (int p = 0; p < 2; ++p) {
    int rr = p * 32 + row;
    int sw = (seg ^ ((rr >> 3) & 7)) * 8;
    *(uint4*)(dst + rr * dstride + seg * 8) = *(uint4*)(tile + rr * 80 + sw);
  }
}

// Wq|Wk|Wv (each 256x2048 fp32, row-major in->out) -> Wt (6144x256 bf16), q/k scaled 0.25
__global__ __launch_bounds__(256) void k_transpose_wqkv(const float* __restrict__ Wq,
                                                        const float* __restrict__ Wk,
                                                        const float* __restrict__ Wv,
                                                        u16* __restrict__ Wt) {
  __shared__ u16 tile[64 * 80];
  const int o0 = blockIdx.x * 64, i0 = blockIdx.y * 64;
  const float* src; float scale = 0.25f; int oc0 = o0;
  if (o0 < 2048)      { src = Wq; }
  else if (o0 < 4096) { src = Wk; oc0 = o0 - 2048; }
  else                { src = Wv; oc0 = o0 - 4096; scale = 1.0f; }
  transpose64f(src + i0 * 2048 + oc0, 2048, Wt + o0 * 256 + i0, 256, scale, tile);
}

// Wu (2048x256 fp32) -> Wut (256x2048 bf16)
__global__ __launch_bounds__(256) void k_transpose_wu(const float* __restrict__ Wu,
                                                      u16* __restrict__ Wut) {
  __shared__ u16 tile[64 * 80];
  const int c0 = blockIdx.x * 64, r0 = blockIdx.y * 64;
  transpose64f(Wu + r0 * 256 + c0, 256, Wut + c0 * 2048 + r0, 2048, 1.0f, tile);
}

// V slice of qkv (b,t,h,d) -> vt (b,h,d,t), bf16
__global__ __launch_bounds__(256) void k_transpose_v(const u16* __restrict__ qkv,
                                                     u16* __restrict__ vt) {
  __shared__ u16 tile[64 * 80];
  const int bh = blockIdx.z;
  const int b = bh >> 3, h = bh & 7;
  const int t0 = blockIdx.y * 64, d0 = blockIdx.x * 64;
  const u16* src = qkv + ((size_t)(b * 1024 + t0)) * 6144 + 4096 + h * 256 + d0;
  u16* dst = vt + ((size_t)(bh * 256 + d0)) * 1024 + t0;
  transpose64(src, 6144, dst, 1024, tile);
}

// ---------------- QKV projection GEMM ----------------
// A = xb (8192x256 bf16), Bt = Wt (6144x256), C = qkv (8192x6144 bf16)
__global__ __launch_bounds__(256) void k_gemm_qkv(const u16* __restrict__ A,
                                                  const u16* __restrict__ Bt,
                                                  u16* __restrict__ C) {
  __shared__ u16 As[128 * 32];
  __shared__ u16 Bs[128 * 32];
  const int m0 = blockIdx.y * 128, n0 = blockIdx.x * 128;
  const int tid = threadIdx.x, w = tid >> 6, lane = tid & 63;
  const int q = lane >> 4, r = lane & 15;
  const int wm = (w >> 1) * 64, wn = (w & 1) * 64;
  const int bo0 = w * 2048 + lane * 16;
  const int row0 = bo0 >> 6, col0 = (bo0 & 63) >> 1;
  const int bo1 = bo0 + 1024;
  const int row1 = bo1 >> 6, col1 = (bo1 & 63) >> 1;
  f32x4 acc[4][4] = {};
  for (int kt = 0; kt < 256; kt += 32) {
    __syncthreads();
    gl_lds16(A + (m0 + row0) * 256 + kt + col0, As + w * 1024);
    gl_lds16(A + (m0 + row1) * 256 + kt + col1, As + w * 1024 + 512);
    gl_lds16(Bt + (n0 + row0) * 256 + kt + col0, Bs + w * 1024);
    gl_lds16(Bt + (n0 + row1) * 256 + kt + col1, Bs + w * 1024 + 512);
    __syncthreads();
    bf16x8 af[4], bf[4];
#pragma unroll
    for (int mb = 0; mb < 4; ++mb) af[mb] = *(const bf16x8*)(As + (wm + mb * 16 + r) * 32 + q * 8);
#pragma unroll
    for (int nb = 0; nb < 4; ++nb) bf[nb] = *(const bf16x8*)(Bs + (wn + nb * 16 + r) * 32 + q * 8);
#pragma unroll
    for (int mb = 0; mb < 4; ++mb)
#pragma unroll
      for (int nb = 0; nb < 4; ++nb)
        acc[mb][nb] = __builtin_amdgcn_mfma_f32_16x16x32_bf16(af[mb], bf[nb], acc[mb][nb], 0, 0, 0);
  }
#pragma unroll
  for (int mb = 0; mb < 4; ++mb)
#pragma unroll
    for (int nb = 0; nb < 4; ++nb) {
      const int nn = n0 + wn + nb * 16 + r;
#pragma unroll
      for (int reg = 0; reg < 4; ++reg) {
        const int mm = m0 + wm + mb * 16 + q * 4 + reg;
        C[(size_t)mm * 6144 + nn] = f2bf(acc[mb][nb][reg]);
      }
    }
}

// ---------------- fused flash attention (S^T / O^T formulation) ----------------
// qkv: (8192 x 6144) [Q|K|V], Q/K pre-scaled 1/4 via weights. vt: (b,h,d=256,t=1024).
// att out: (8192 x 2048) bf16.
// K/V staged fragment-major with swizzle: unit = blk*64 + q*16 + ((r+q)&15), 8 u16 each.
// -> all ds_read_b128 / staging ds_write_b128 conflict-free (<=2-way).
__global__ __launch_bounds__(256) void k_attn(const u16* __restrict__ qkv,
                                              const u16* __restrict__ vt,
                                              u16* __restrict__ att) {
  __shared__ u16 smem[16896];   // K frag [0,8192) | V frag [8192,16384) | Os overlays [0,16896)
  const int blk = blockIdx.x;
  const int qt = blk >> 6, bh = blk & 63;       // bh-major: (b,h) sharers -> same XCD
  const int b = bh >> 3, h = bh & 7;
  const int tid = threadIdx.x, w = tid >> 6, lane = tid & 63;
  const int q = lane >> 4, r = lane & 15;
  const int t0 = qt * 64 + w * 16;

  // Q fragments from global (one-time); B-operand layout == old A-operand data
  const u16* Qg = qkv + ((size_t)(b * 1024 + t0 + r)) * 6144 + h * 256;
  bf16x8 qf[8];
#pragma unroll
  for (int kc = 0; kc < 8; ++kc) qf[kc] = *(const bf16x8*)(Qg + kc * 32 + q * 8);

  float m_i = -3.0e38f, l_i = 0.0f;
  f32x4 o[16] = {};   // O^T: o[db][reg] = O[qrow=t0+r][d=db*16+q*4+reg]

  const u16* Kg = qkv + (size_t)b * 1024 * 6144 + 2048 + h * 256;
  const u16* Vg = vt + (size_t)(b * 8 + h) * 256 * 1024;

  const int kc_s = (tid & 31) >> 2, kq_s = tid & 3;   // K staging decode
  const int db_s = tid >> 4, vr_s = tid & 15;          // V staging decode

  for (int sc = 0; sc < 1024; sc += 32) {
    __syncthreads();  // all waves done reading prev chunk
    // ---- stage K (32 keys x 256 d) into fragment-major swizzled layout
    {
      uint4 kv[4];
#pragma unroll
      for (int p = 0; p < 4; ++p) {
        int key = p * 8 + (tid >> 5);
        kv[p] = *(const uint4*)(Kg + (size_t)(sc + key) * 6144 + (tid & 31) * 8);
      }
#pragma unroll
      for (int p = 0; p < 4; ++p) {
        int key = p * 8 + (tid >> 5);
        int sb = key >> 4, kr = key & 15;
        int unit = (kc_s * 2 + sb) * 64 + kq_s * 16 + ((kr + kq_s) & 15);
        *(uint4*)(smem + unit * 8) = kv[p];
      }
    }
    // ---- stage V^T (256 d x 32 keys) into fragment-major swizzled layout
    {
      uint4 vv[4];
#pragma unroll
      for (int p = 0; p < 4; ++p)
        vv[p] = *(const uint4*)(Vg + (size_t)tid * 1024 + sc + p * 8);
#pragma unroll
      for (int p = 0; p < 4; ++p) {
        int unit = db_s * 64 + p * 16 + ((vr_s + p) & 15);
        *(uint4*)(smem + 8192 + unit * 8) = vv[p];
      }
    }
    __syncthreads();

    // ---- S^T = K Q^T (two 16-key blocks); C-layout: row=key=q*4+reg, col=qrow=r
    f32x4 s0 = {}, s1 = {};
#pragma unroll
    for (int kc = 0; kc < 8; ++kc) {
      bf16x8 k0 = *(const bf16x8*)(smem + ((kc * 2 + 0) * 64 + q * 16 + ((r + q) & 15)) * 8);
      bf16x8 k1 = *(const bf16x8*)(smem + ((kc * 2 + 1) * 64 + q * 16 + ((r + q) & 15)) * 8);
      s0 = __builtin_amdgcn_mfma_f32_16x16x32_bf16(k0, qf[kc], s0, 0, 0, 0);
      s1 = __builtin_amdgcn_mfma_f32_16x16x32_bf16(k1, qf[kc], s1, 0, 0, 0);
    }

    // ---- online softmax: this lane's 8 scores all belong to qrow r
    float vmax = fmaxf(fmaxf(fmaxf(s0[0], s0[1]), fmaxf(s0[2], s0[3])),
                       fmaxf(fmaxf(s1[0], s1[1]), fmaxf(s1[2], s1[3])));
    vmax = fmaxf(vmax, __shfl_xor(vmax, 16));
    vmax = fmaxf(vmax, __shfl_xor(vmax, 32));
    float mn = fmaxf(m_i, vmax);
    float al = exp2f((m_i - mn) * LOG2E);
    float pa[4], pb[4];
    float rs = 0.0f;
#pragma unroll
    for (int reg = 0; reg < 4; ++reg) {
      pa[reg] = exp2f((s0[reg] - mn) * LOG2E);
      pb[reg] = exp2f((s1[reg] - mn) * LOG2E);
      rs += pa[reg] + pb[reg];
    }
    rs += __shfl_xor(rs, 16);
    rs += __shfl_xor(rs, 32);
    l_i = l_i * al + rs;
    m_i = mn;
    if (__any(al < 0.99999f)) {
#pragma unroll
      for (int db = 0; db < 16; ++db) {
        f32x4 t = o[db];
#pragma unroll
        for (int reg = 0; reg < 4; ++reg) t[reg] *= al;
        o[db] = t;
      }
    }

    // ---- P^T B-fragment via packed shuffles (no LDS round-trip)
    // lane (q,r) needs P[qrow=r][s=q*8+j]; source lanes (q&1)*32+r (j<4) / +16 (j>=4),
    // low half = keys 0..15 (pa), high half = keys 16..31 (pb); select by q>=2.
    uint32_t pk[4];
#pragma unroll
    for (int reg = 0; reg < 4; ++reg)
      pk[reg] = (uint32_t)f2bf(pa[reg]) | ((uint32_t)f2bf(pb[reg]) << 16);
    const int srcA = ((q & 1) << 5) + r;
    const int srcB = srcA + 16;
    uint32_t tt[8];
#pragma unroll
    for (int reg = 0; reg < 4; ++reg) tt[reg] = (uint32_t)__shfl((int)pk[reg], srcA);
#pragma unroll
    for (int reg = 0; reg < 4; ++reg) tt[4 + reg] = (uint32_t)__shfl((int)pk[reg], srcB);
    union { bf16x8 v; u16 e[8]; } pf;
    const bool hi = (q >= 2);
#pragma unroll
    for (int j = 0; j < 8; ++j)
      pf.e[j] = hi ? (u16)(tt[j] >> 16) : (u16)(tt[j] & 0xffffu);

    // ---- O^T += V^T P^T
#pragma unroll
    for (int db = 0; db < 16; ++db) {
      bf16x8 vf = *(const bf16x8*)(smem + 8192 + (db * 64 + q * 16 + ((r + q) & 15)) * 8);
      o[db] = __builtin_amdgcn_mfma_f32_16x16x32_bf16(vf, pf.v, o[db], 0, 0, 0);
    }
  }

  // ---- epilogue: normalize, stage O[row][d] in LDS (b64 writes), coalesced global stores
  float rl = 1.0f / l_i;
  __syncthreads();  // all waves done with K/V region before overlay
  u16* Os = smem + w * 4224;  // per-wave 16 rows x pitch 264
#pragma unroll
  for (int db = 0; db < 16; ++db) {
    uint32_t lo = (uint32_t)f2bf(o[db][0] * rl) | ((uint32_t)f2bf(o[db][1] * rl) << 16);
    uint32_t hi2 = (uint32_t)f2bf(o[db][2] * rl) | ((uint32_t)f2bf(o[db][3] * rl) << 16);
    uint2 val; val.x = lo; val.y = hi2;
    *(uint2*)(Os + r * 264 + db * 16 + q * 4) = val;
  }
  asm volatile("s_waitcnt lgkmcnt(0)" ::: "memory");
  u16* Ag = att + ((size_t)(b * 1024 + t0)) * 2048 + h * 256;
#pragma unroll
  for (int p = 0; p < 8; ++p) {
    int idx = (p * 64 + lane) * 8;
    int row = idx >> 8, col = idx & 255;
    *(uint4*)(Ag + (size_t)row * 2048 + col) = *(uint4*)(Os + row * 264 + col);
  }
}

// ---------------- unify GEMM + bias ----------------
// A = att (8192x2048), Bt = Wut (256x2048), bu fp32, out FP32 (8192x256)
__global__ __launch_bounds__(256) void k_gemm_out(const u16* __restrict__ A,
                                                  const u16* __restrict__ Bt,
                                                  const float* __restrict__ bu,
                                                  float* __restrict__ C) {
  __shared__ u16 As[128 * 32];
  __shared__ u16 Bs[64 * 32];
  const int m0 = blockIdx.y * 128, n0 = blockIdx.x * 64;
  const int tid = threadIdx.x, w = tid >> 6, lane = tid & 63;
  const int q = lane >> 4, r = lane & 15;
  const int wm = (w >> 1) * 64, wn = (w & 1) * 32;
  const int boA0 = w * 2048 + lane * 16;
  const int rA0 = boA0 >> 6, cA0 = (boA0 & 63) >> 1;
  const int boA1 = boA0 + 1024;
  const int rA1 = boA1 >> 6, cA1 = (boA1 & 63) >> 1;
  const int boB = w * 1024 + lane * 16;
  const int rB = boB >> 6, cB = (boB & 63) >> 1;
  f32x4 acc[4][2] = {};
  for (int kt = 0; kt < 2048; kt += 32) {
    __syncthreads();
    gl_lds16(A + (size_t)(m0 + rA0) * 2048 + kt + cA0, As + w * 1024);
    gl_lds16(A + (size_t)(m0 + rA1) * 2048 + kt + cA1, As + w * 1024 + 512);
    gl_lds16(Bt + (size_t)(n0 + rB) * 2048 + kt + cB, Bs + w * 512);
    __syncthreads();
    bf16x8 af[4], bf[2];
#pragma unroll
    for (int mb = 0; mb < 4; ++mb) af[mb] = *(const bf16x8*)(As + (wm + mb * 16 + r) * 32 + q * 8);
#pragma unroll
    for (int nb = 0; nb < 2; ++nb) bf[nb] = *(const bf16x8*)(Bs + (wn + nb * 16 + r) * 32 + q * 8);
#pragma unroll
    for (int mb = 0; mb < 4; ++mb)
#pragma unroll
      for (int nb = 0; nb < 2; ++nb)
        acc[mb][nb] = __builtin_amdgcn_mfma_f32_16x16x32_bf16(af[mb], bf[nb], acc[mb][nb], 0, 0, 0);
  }
  float bias[2];
#pragma unroll
  for (int nb = 0; nb < 2; ++nb) bias[nb] = bu[n0 + wn + nb * 16 + r];
#pragma unroll
  for (int mb = 0; mb < 4; ++mb)
#pragma unroll
    for (int nb = 0; nb < 2; ++nb) {
      const int nn = n0 + wn + nb * 16 + r;
#pragma unroll
      for (int reg = 0; reg < 4; ++reg) {
        const int mm = m0 + wm + mb * 16 + q * 4 + reg;
        C[(size_t)mm * 256 + nn] = acc[mb][nb][reg] + bias[nb];
      }
    }
}

extern "C" void kernel_launch(void* const* d_in, const int* in_sizes, int n_in,
                              void* d_out, int out_size, void* d_ws, size_t ws_size,
                              hipStream_t stream) {
  const float* x  = (const float*)d_in[0];   // (8192, 256) fp32
  const float* Wq = (const float*)d_in[1];   // (256, 2048) fp32
  const float* Wk = (const float*)d_in[2];
  const float* Wv = (const float*)d_in[3];
  const float* Wu = (const float*)d_in[4];   // (2048, 256) fp32
  const float* bu = (const float*)d_in[5];   // (256,) fp32
  float* outp = (float*)d_out;               // (8192, 256) fp32

  char* ws = (char*)d_ws;
  u16* qkv   = (u16*)(ws);                          // 8192*6144*2  = 100663296
  u16* vt    = (u16*)(ws + 100663296);              // 64*256*1024*2 = 33554432
  u16* attb  = (u16*)(ws + 134217728);              // 8192*2048*2  = 33554432
  u16* wqkvt = (u16*)(ws + 167772160);              // 6144*256*2   = 3145728
  u16* wut   = (u16*)(ws + 170917888);              // 256*2048*2   = 1048576
  u16* xb    = (u16*)(ws + 171966464);              // 8192*256*2   = 4194304
  (void)in_sizes; (void)n_in; (void)out_size; (void)ws_size;

  dim3 blk(256);
  k_cvt_x<<<dim3(2048), blk, 0, stream>>>(x, xb);
  k_transpose_wqkv<<<dim3(96, 4), blk, 0, stream>>>(Wq, Wk, Wv, wqkvt);
  k_transpose_wu<<<dim3(4, 32), blk, 0, stream>>>(Wu, wut);
  k_gemm_qkv<<<dim3(48, 64), blk, 0, stream>>>(xb, wqkvt, qkv);
  k_transpose_v<<<dim3(4, 16, 64), blk, 0, stream>>>(qkv, vt);
  k_attn<<<dim3(1024), blk, 0, stream>>>(qkv, vt, attb);
  k_gemm_out<<<dim3(4, 64), blk, 0, stream>>>(attb, wut, bu, outp);
}

// Round 5
// 282.393 us; speedup vs baseline: 1.3331x; 1.1441x over previous
//
#include <hip/hip_runtime.h>
#include <stdint.h>

typedef unsigned short u16;
typedef __attribute__((ext_vector_type(8))) short bf16x8;
typedef __attribute__((ext_vector_type(4))) float f32x4;

#define LOG2E 1.44269504088896340736f

__device__ __forceinline__ float bf2f(u16 u) {
  union { uint32_t u; float f; } v; v.u = ((uint32_t)u) << 16; return v.f;
}
__device__ __forceinline__ u16 f2bf(float f) {
  union { float f; uint32_t u; } v; v.f = f;
  uint32_t r = v.u + 0x7fffu + ((v.u >> 16) & 1u);
  return (u16)(r >> 16);
}

// async global->LDS, 16B per lane; lds ptr must be wave-uniform base (HW adds lane*16)
__device__ __forceinline__ void gl_lds16(const u16* g, u16* l) {
  __builtin_amdgcn_global_load_lds((const __attribute__((address_space(1))) void*)g,
                                   (__attribute__((address_space(3))) void*)l, 16, 0, 0);
}

// ---------------- x: fp32 -> bf16 ----------------
__global__ __launch_bounds__(256) void k_cvt_x(const float* __restrict__ x,
                                               u16* __restrict__ xb) {
  const int i = blockIdx.x * 256 + threadIdx.x;
  float4 v = ((const float4*)x)[i];
  ushort4 o;
  o.x = f2bf(v.x); o.y = f2bf(v.y); o.z = f2bf(v.z); o.w = f2bf(v.w);
  ((ushort4*)xb)[i] = o;
}

// ---------------- transpose fp32 -> bf16 (64x64 tile via LDS, XOR-swizzled) ----------------
__device__ __forceinline__ void transpose64f(const float* src, int sstride,
                                             u16* dst, int dstride,
                                             float scale, u16* tile /*64*80*/) {
  const int tid = threadIdx.x;
  const int row = tid >> 3, seg = tid & 7;
#pragma unroll
  for (int p = 0; p < 2; ++p) {
    int rr = p * 32 + row;
    int rw = rr ^ (seg * 8);
    float4 a = *(const float4*)(src + rr * sstride + seg * 8);
    float4 b = *(const float4*)(src + rr * sstride + seg * 8 + 4);
    tile[(seg * 8 + 0) * 80 + rw] = f2bf(a.x * scale);
    tile[(seg * 8 + 1) * 80 + rw] = f2bf(a.y * scale);
    tile[(seg * 8 + 2) * 80 + rw] = f2bf(a.z * scale);
    tile[(seg * 8 + 3) * 80 + rw] = f2bf(a.w * scale);
    tile[(seg * 8 + 4) * 80 + rw] = f2bf(b.x * scale);
    tile[(seg * 8 + 5) * 80 + rw] = f2bf(b.y * scale);
    tile[(seg * 8 + 6) * 80 + rw] = f2bf(b.z * scale);
    tile[(seg * 8 + 7) * 80 + rw] = f2bf(b.w * scale);
  }
  __syncthreads();
#pragma unroll
  for (int p = 0; p < 2; ++p) {
    int rr = p * 32 + row;
    int sw = (seg ^ ((rr >> 3) & 7)) * 8;
    *(uint4*)(dst + rr * dstride + seg * 8) = *(uint4*)(tile + rr * 80 + sw);
  }
}

// ---------------- transpose bf16 -> bf16 (for V), XOR-swizzled ----------------
__device__ __forceinline__ void transpose64(const u16* src, int sstride,
                                            u16* dst, int dstride, u16* tile) {
  const int tid = threadIdx.x;
  const int row = tid >> 3, seg = tid & 7;
  union { uint4 u; u16 s[8]; } tv;
#pragma unroll
  for (int p = 0; p < 2; ++p) {
    int rr = p * 32 + row;
    int rw = rr ^ (seg * 8);
    tv.u = *(const uint4*)(src + rr * sstride + seg * 8);
#pragma unroll
    for (int j = 0; j < 8; ++j)
      tile[(seg * 8 + j) * 80 + rw] = tv.s[j];
  }
  __syncthreads();
#pragma unroll
  for (int p = 0; p < 2; ++p) {
    int rr = p * 32 + row;
    int sw = (seg ^ ((rr >> 3) & 7)) * 8;
    *(uint4*)(dst + rr * dstride + seg * 8) = *(uint4*)(tile + rr * 80 + sw);
  }
}

// Wq|Wk|Wv (each 256x2048 fp32) -> Wt (6144x256 bf16), q/k scaled 0.25
__global__ __launch_bounds__(256) void k_transpose_wqkv(const float* __restrict__ Wq,
                                                        const float* __restrict__ Wk,
                                                        const float* __restrict__ Wv,
                                                        u16* __restrict__ Wt) {
  __shared__ u16 tile[64 * 80];
  const int o0 = blockIdx.x * 64, i0 = blockIdx.y * 64;
  const float* src; float scale = 0.25f; int oc0 = o0;
  if (o0 < 2048)      { src = Wq; }
  else if (o0 < 4096) { src = Wk; oc0 = o0 - 2048; }
  else                { src = Wv; oc0 = o0 - 4096; scale = 1.0f; }
  transpose64f(src + i0 * 2048 + oc0, 2048, Wt + o0 * 256 + i0, 256, scale, tile);
}

// Wu (2048x256 fp32) -> Wut (256x2048 bf16)
__global__ __launch_bounds__(256) void k_transpose_wu(const float* __restrict__ Wu,
                                                      u16* __restrict__ Wut) {
  __shared__ u16 tile[64 * 80];
  const int c0 = blockIdx.x * 64, r0 = blockIdx.y * 64;
  transpose64f(Wu + r0 * 256 + c0, 256, Wut + c0 * 2048 + r0, 2048, 1.0f, tile);
}

// V slice of qkv (b,t,h,d) -> vt (b,h,d,t), bf16
__global__ __launch_bounds__(256) void k_transpose_v(const u16* __restrict__ qkv,
                                                     u16* __restrict__ vt) {
  __shared__ u16 tile[64 * 80];
  const int bh = blockIdx.z;
  const int b = bh >> 3, h = bh & 7;
  const int t0 = blockIdx.y * 64, d0 = blockIdx.x * 64;
  const u16* src = qkv + ((size_t)(b * 1024 + t0)) * 6144 + 4096 + h * 256 + d0;
  u16* dst = vt + ((size_t)(bh * 256 + d0)) * 1024 + t0;
  transpose64(src, 6144, dst, 1024, tile);
}

// ---------------- QKV projection GEMM ----------------
__global__ __launch_bounds__(256) void k_gemm_qkv(const u16* __restrict__ A,
                                                  const u16* __restrict__ Bt,
                                                  u16* __restrict__ C) {
  __shared__ u16 As[128 * 32];
  __shared__ u16 Bs[128 * 32];
  const int m0 = blockIdx.y * 128, n0 = blockIdx.x * 128;
  const int tid = threadIdx.x, w = tid >> 6, lane = tid & 63;
  const int q = lane >> 4, r = lane & 15;
  const int wm = (w >> 1) * 64, wn = (w & 1) * 64;
  const int bo0 = w * 2048 + lane * 16;
  const int row0 = bo0 >> 6, col0 = (bo0 & 63) >> 1;
  const int bo1 = bo0 + 1024;
  const int row1 = bo1 >> 6, col1 = (bo1 & 63) >> 1;
  f32x4 acc[4][4] = {};
  for (int kt = 0; kt < 256; kt += 32) {
    __syncthreads();
    gl_lds16(A + (m0 + row0) * 256 + kt + col0, As + w * 1024);
    gl_lds16(A + (m0 + row1) * 256 + kt + col1, As + w * 1024 + 512);
    gl_lds16(Bt + (n0 + row0) * 256 + kt + col0, Bs + w * 1024);
    gl_lds16(Bt + (n0 + row1) * 256 + kt + col1, Bs + w * 1024 + 512);
    __syncthreads();
    bf16x8 af[4], bf[4];
#pragma unroll
    for (int mb = 0; mb < 4; ++mb) af[mb] = *(const bf16x8*)(As + (wm + mb * 16 + r) * 32 + q * 8);
#pragma unroll
    for (int nb = 0; nb < 4; ++nb) bf[nb] = *(const bf16x8*)(Bs + (wn + nb * 16 + r) * 32 + q * 8);
#pragma unroll
    for (int mb = 0; mb < 4; ++mb)
#pragma unroll
      for (int nb = 0; nb < 4; ++nb)
        acc[mb][nb] = __builtin_amdgcn_mfma_f32_16x16x32_bf16(af[mb], bf[nb], acc[mb][nb], 0, 0, 0);
  }
#pragma unroll
  for (int mb = 0; mb < 4; ++mb)
#pragma unroll
    for (int nb = 0; nb < 4; ++nb) {
      const int nn = n0 + wn + nb * 16 + r;
#pragma unroll
      for (int reg = 0; reg < 4; ++reg) {
        const int mm = m0 + wm + mb * 16 + q * 4 + reg;
        C[(size_t)mm * 6144 + nn] = f2bf(acc[mb][nb][reg]);
      }
    }
}

// ---------------- fused flash attention (S^T / O^T, 32 q-rows per wave) ----------------
// Each wave handles 32 q-rows (two 16-row groups A/B); K/V fragments read once, used twice.
__global__ __launch_bounds__(256, 2) void k_attn(const u16* __restrict__ qkv,
                                                 const u16* __restrict__ vt,
                                                 u16* __restrict__ att) {
  __shared__ u16 smem[16896];   // K frag [0,8192) | V frag [8192,16384) | Os overlay
  const int blk = blockIdx.x;
  const int qt = blk >> 6, bh = blk & 63;       // bh-major: XCD = h -> L2 chunk sharing
  const int b = bh >> 3, h = bh & 7;
  const int tid = threadIdx.x, w = tid >> 6, lane = tid & 63;
  const int q = lane >> 4, r = lane & 15;
  const int t0 = qt * 128 + w * 32;

  // Q B-fragments (two row groups), loaded once
  const u16* QgA = qkv + ((size_t)(b * 1024 + t0 + r)) * 6144 + h * 256;
  const u16* QgB = QgA + (size_t)16 * 6144;
  bf16x8 qfA[8], qfB[8];
#pragma unroll
  for (int kc = 0; kc < 8; ++kc) {
    qfA[kc] = *(const bf16x8*)(QgA + kc * 32 + q * 8);
    qfB[kc] = *(const bf16x8*)(QgB + kc * 32 + q * 8);
  }

  float mA = -3.0e38f, lA = 0.0f, mB = -3.0e38f, lB = 0.0f;
  f32x4 oA[16] = {}, oB[16] = {};

  const u16* Kg = qkv + (size_t)b * 1024 * 6144 + 2048 + h * 256;
  const u16* Vg = vt + (size_t)(b * 8 + h) * 256 * 1024;

  const int kc_s = (tid & 31) >> 2, kq_s = tid & 3;   // K staging decode
  const int db_s = tid >> 4, vr_s = tid & 15;          // V staging decode

  for (int sc = 0; sc < 1024; sc += 32) {
    __syncthreads();
    // ---- stage K (32 keys x 256 d), fragment-major swizzled
    {
      uint4 kv[4];
#pragma unroll
      for (int p = 0; p < 4; ++p) {
        int key = p * 8 + (tid >> 5);
        kv[p] = *(const uint4*)(Kg + (size_t)(sc + key) * 6144 + (tid & 31) * 8);
      }
#pragma unroll
      for (int p = 0; p < 4; ++p) {
        int key = p * 8 + (tid >> 5);
        int sb = key >> 4, kr = key & 15;
        int unit = (kc_s * 2 + sb) * 64 + kq_s * 16 + ((kr + kq_s) & 15);
        *(uint4*)(smem + unit * 8) = kv[p];
      }
    }
    // ---- stage V^T (256 d x 32 keys), fragment-major swizzled
    {
      uint4 vv[4];
#pragma unroll
      for (int p = 0; p < 4; ++p)
        vv[p] = *(const uint4*)(Vg + (size_t)tid * 1024 + sc + p * 8);
#pragma unroll
      for (int p = 0; p < 4; ++p) {
        int unit = db_s * 64 + p * 16 + ((vr_s + p) & 15);
        *(uint4*)(smem + 8192 + unit * 8) = vv[p];
      }
    }
    __syncthreads();

    // ---- S^T = K Q^T for both row groups; each K fragment feeds 2 MFMAs
    f32x4 s0A = {}, s1A = {}, s0B = {}, s1B = {};
#pragma unroll
    for (int kc = 0; kc < 8; ++kc) {
      bf16x8 k0 = *(const bf16x8*)(smem + ((kc * 2 + 0) * 64 + q * 16 + ((r + q) & 15)) * 8);
      bf16x8 k1 = *(const bf16x8*)(smem + ((kc * 2 + 1) * 64 + q * 16 + ((r + q) & 15)) * 8);
      s0A = __builtin_amdgcn_mfma_f32_16x16x32_bf16(k0, qfA[kc], s0A, 0, 0, 0);
      s1A = __builtin_amdgcn_mfma_f32_16x16x32_bf16(k1, qfA[kc], s1A, 0, 0, 0);
      s0B = __builtin_amdgcn_mfma_f32_16x16x32_bf16(k0, qfB[kc], s0B, 0, 0, 0);
      s1B = __builtin_amdgcn_mfma_f32_16x16x32_bf16(k1, qfB[kc], s1B, 0, 0, 0);
    }

    // ---- online softmax + P^T fragment, group A
    union { bf16x8 v; u16 e[8]; } pfA, pfB;
    float alA, alB;
    {
      float vmax = fmaxf(fmaxf(fmaxf(s0A[0], s0A[1]), fmaxf(s0A[2], s0A[3])),
                         fmaxf(fmaxf(s1A[0], s1A[1]), fmaxf(s1A[2], s1A[3])));
      vmax = fmaxf(vmax, __shfl_xor(vmax, 16));
      vmax = fmaxf(vmax, __shfl_xor(vmax, 32));
      float mn = fmaxf(mA, vmax);
      alA = exp2f((mA - mn) * LOG2E);
      float pa[4], pb[4], rs = 0.0f;
#pragma unroll
      for (int reg = 0; reg < 4; ++reg) {
        pa[reg] = exp2f((s0A[reg] - mn) * LOG2E);
        pb[reg] = exp2f((s1A[reg] - mn) * LOG2E);
        rs += pa[reg] + pb[reg];
      }
      rs += __shfl_xor(rs, 16); rs += __shfl_xor(rs, 32);
      lA = lA * alA + rs; mA = mn;
      uint32_t pk[4];
#pragma unroll
      for (int reg = 0; reg < 4; ++reg)
        pk[reg] = (uint32_t)f2bf(pa[reg]) | ((uint32_t)f2bf(pb[reg]) << 16);
      const int srcA = ((q & 1) << 5) + r, srcB = srcA + 16;
      uint32_t tt[8];
#pragma unroll
      for (int reg = 0; reg < 4; ++reg) tt[reg] = (uint32_t)__shfl((int)pk[reg], srcA);
#pragma unroll
      for (int reg = 0; reg < 4; ++reg) tt[4 + reg] = (uint32_t)__shfl((int)pk[reg], srcB);
      const bool hi = (q >= 2);
#pragma unroll
      for (int j = 0; j < 8; ++j)
        pfA.e[j] = hi ? (u16)(tt[j] >> 16) : (u16)(tt[j] & 0xffffu);
    }
    // ---- group B
    {
      float vmax = fmaxf(fmaxf(fmaxf(s0B[0], s0B[1]), fmaxf(s0B[2], s0B[3])),
                         fmaxf(fmaxf(s1B[0], s1B[1]), fmaxf(s1B[2], s1B[3])));
      vmax = fmaxf(vmax, __shfl_xor(vmax, 16));
      vmax = fmaxf(vmax, __shfl_xor(vmax, 32));
      float mn = fmaxf(mB, vmax);
      alB = exp2f((mB - mn) * LOG2E);
      float pa[4], pb[4], rs = 0.0f;
#pragma unroll
      for (int reg = 0; reg < 4; ++reg) {
        pa[reg] = exp2f((s0B[reg] - mn) * LOG2E);
        pb[reg] = exp2f((s1B[reg] - mn) * LOG2E);
        rs += pa[reg] + pb[reg];
      }
      rs += __shfl_xor(rs, 16); rs += __shfl_xor(rs, 32);
      lB = lB * alB + rs; mB = mn;
      uint32_t pk[4];
#pragma unroll
      for (int reg = 0; reg < 4; ++reg)
        pk[reg] = (uint32_t)f2bf(pa[reg]) | ((uint32_t)f2bf(pb[reg]) << 16);
      const int srcA = ((q & 1) << 5) + r, srcB = srcA + 16;
      uint32_t tt[8];
#pragma unroll
      for (int reg = 0; reg < 4; ++reg) tt[reg] = (uint32_t)__shfl((int)pk[reg], srcA);
#pragma unroll
      for (int reg = 0; reg < 4; ++reg) tt[4 + reg] = (uint32_t)__shfl((int)pk[reg], srcB);
      const bool hi = (q >= 2);
#pragma unroll
      for (int j = 0; j < 8; ++j)
        pfB.e[j] = hi ? (u16)(tt[j] >> 16) : (u16)(tt[j] & 0xffffu);
    }

    if (__any(alA < 0.99999f)) {
#pragma unroll
      for (int db = 0; db < 16; ++db) {
        f32x4 t = oA[db];
#pragma unroll
        for (int reg = 0; reg < 4; ++reg) t[reg] *= alA;
        oA[db] = t;
      }
    }
    if (__any(alB < 0.99999f)) {
#pragma unroll
      for (int db = 0; db < 16; ++db) {
        f32x4 t = oB[db];
#pragma unroll
        for (int reg = 0; reg < 4; ++reg) t[reg] *= alB;
        oB[db] = t;
      }
    }

    // ---- O^T += V^T P^T; each V fragment feeds 2 MFMAs
#pragma unroll
    for (int db = 0; db < 16; ++db) {
      bf16x8 vf = *(const bf16x8*)(smem + 8192 + (db * 64 + q * 16 + ((r + q) & 15)) * 8);
      oA[db] = __builtin_amdgcn_mfma_f32_16x16x32_bf16(vf, pfA.v, oA[db], 0, 0, 0);
      oB[db] = __builtin_amdgcn_mfma_f32_16x16x32_bf16(vf, pfB.v, oB[db], 0, 0, 0);
    }
  }

  // ---- epilogue: two passes through per-wave Os buffer (16 rows x pitch 264)
  __syncthreads();  // all waves done with K/V region before overlay
  u16* Os = smem + w * 4224;
  float rlA = 1.0f / lA, rlB = 1.0f / lB;
#pragma unroll
  for (int pass = 0; pass < 2; ++pass) {
    const f32x4* o = pass ? oB : oA;
    const float rl = pass ? rlB : rlA;
    const int tb = t0 + pass * 16;
    __syncthreads();  // prior pass's reads done before overwrite (cheap, 2x)
#pragma unroll
    for (int db = 0; db < 16; ++db) {
      uint32_t lo = (uint32_t)f2bf(o[db][0] * rl) | ((uint32_t)f2bf(o[db][1] * rl) << 16);
      uint32_t hi2 = (uint32_t)f2bf(o[db][2] * rl) | ((uint32_t)f2bf(o[db][3] * rl) << 16);
      uint2 val; val.x = lo; val.y = hi2;
      *(uint2*)(Os + r * 264 + db * 16 + q * 4) = val;
    }
    asm volatile("s_waitcnt lgkmcnt(0)" ::: "memory");
    u16* Ag = att + ((size_t)(b * 1024 + tb)) * 2048 + h * 256;
#pragma unroll
    for (int p = 0; p < 8; ++p) {
      int idx = (p * 64 + lane) * 8;
      int row = idx >> 8, col = idx & 255;
      *(uint4*)(Ag + (size_t)row * 2048 + col) = *(uint4*)(Os + row * 264 + col);
    }
  }
}

// ---------------- unify GEMM + bias ----------------
__global__ __launch_bounds__(256) void k_gemm_out(const u16* __restrict__ A,
                                                  const u16* __restrict__ Bt,
                                                  const float* __restrict__ bu,
                                                  float* __restrict__ C) {
  __shared__ u16 As[128 * 32];
  __shared__ u16 Bs[64 * 32];
  const int m0 = blockIdx.y * 128, n0 = blockIdx.x * 64;
  const int tid = threadIdx.x, w = tid >> 6, lane = tid & 63;
  const int q = lane >> 4, r = lane & 15;
  const int wm = (w >> 1) * 64, wn = (w & 1) * 32;
  const int boA0 = w * 2048 + lane * 16;
  const int rA0 = boA0 >> 6, cA0 = (boA0 & 63) >> 1;
  const int boA1 = boA0 + 1024;
  const int rA1 = boA1 >> 6, cA1 = (boA1 & 63) >> 1;
  const int boB = w * 1024 + lane * 16;
  const int rB = boB >> 6, cB = (boB & 63) >> 1;
  f32x4 acc[4][2] = {};
  for (int kt = 0; kt < 2048; kt += 32) {
    __syncthreads();
    gl_lds16(A + (size_t)(m0 + rA0) * 2048 + kt + cA0, As + w * 1024);
    gl_lds16(A + (size_t)(m0 + rA1) * 2048 + kt + cA1, As + w * 1024 + 512);
    gl_lds16(Bt + (size_t)(n0 + rB) * 2048 + kt + cB, Bs + w * 512);
    __syncthreads();
    bf16x8 af[4], bf[2];
#pragma unroll
    for (int mb = 0; mb < 4; ++mb) af[mb] = *(const bf16x8*)(As + (wm + mb * 16 + r) * 32 + q * 8);
#pragma unroll
    for (int nb = 0; nb < 2; ++nb) bf[nb] = *(const bf16x8*)(Bs + (wn + nb * 16 + r) * 32 + q * 8);
#pragma unroll
    for (int mb = 0; mb < 4; ++mb)
#pragma unroll
      for (int nb = 0; nb < 2; ++nb)
        acc[mb][nb] = __builtin_amdgcn_mfma_f32_16x16x32_bf16(af[mb], bf[nb], acc[mb][nb], 0, 0, 0);
  }
  float bias[2];
#pragma unroll
  for (int nb = 0; nb < 2; ++nb) bias[nb] = bu[n0 + wn + nb * 16 + r];
#pragma unroll
  for (int mb = 0; mb < 4; ++mb)
#pragma unroll
    for (int nb = 0; nb < 2; ++nb) {
      const int nn = n0 + wn + nb * 16 + r;
#pragma unroll
      for (int reg = 0; reg < 4; ++reg) {
        const int mm = m0 + wm + mb * 16 + q * 4 + reg;
        C[(size_t)mm * 256 + nn] = acc[mb][nb][reg] + bias[nb];
      }
    }
}

extern "C" void kernel_launch(void* const* d_in, const int* in_sizes, int n_in,
                              void* d_out, int out_size, void* d_ws, size_t ws_size,
                              hipStream_t stream) {
  const float* x  = (const float*)d_in[0];
  const float* Wq = (const float*)d_in[1];
  const float* Wk = (const float*)d_in[2];
  const float* Wv = (const float*)d_in[3];
  const float* Wu = (const float*)d_in[4];
  const float* bu = (const float*)d_in[5];
  float* outp = (float*)d_out;

  char* ws = (char*)d_ws;
  u16* qkv   = (u16*)(ws);                          // 100663296
  u16* vt    = (u16*)(ws + 100663296);              // 33554432
  u16* attb  = (u16*)(ws + 134217728);              // 33554432
  u16* wqkvt = (u16*)(ws + 167772160);              // 3145728
  u16* wut   = (u16*)(ws + 170917888);              // 1048576
  u16* xb    = (u16*)(ws + 171966464);              // 4194304
  (void)in_sizes; (void)n_in; (void)out_size; (void)ws_size;

  dim3 blk(256);
  k_cvt_x<<<dim3(2048), blk, 0, stream>>>(x, xb);
  k_transpose_wqkv<<<dim3(96, 4), blk, 0, stream>>>(Wq, Wk, Wv, wqkvt);
  k_transpose_wu<<<dim3(4, 32), blk, 0, stream>>>(Wu, wut);
  k_gemm_qkv<<<dim3(48, 64), blk, 0, stream>>>(xb, wqkvt, qkv);
  k_transpose_v<<<dim3(4, 16, 64), blk, 0, stream>>>(qkv, vt);
  k_attn<<<dim3(512), blk, 0, stream>>>(qkv, vt, attb);
  k_gemm_out<<<dim3(4, 64), blk, 0, stream>>>(attb, wut, bu, outp);
}

// Round 6
// 272.668 us; speedup vs baseline: 1.3807x; 1.0357x over previous
//
#include <hip/hip_runtime.h>
#include <stdint.h>

typedef unsigned short u16;
typedef __attribute__((ext_vector_type(8))) short bf16x8;
typedef __attribute__((ext_vector_type(4))) float f32x4;

#define LOG2E 1.44269504088896340736f

__device__ __forceinline__ float bf2f(u16 u) {
  union { uint32_t u; float f; } v; v.u = ((uint32_t)u) << 16; return v.f;
}
__device__ __forceinline__ u16 f2bf(float f) {
  union { float f; uint32_t u; } v; v.f = f;
  uint32_t r = v.u + 0x7fffu + ((v.u >> 16) & 1u);
  return (u16)(r >> 16);
}

// async global->LDS, 16B per lane; lds ptr must be wave-uniform base (HW adds lane*16)
__device__ __forceinline__ void gl_lds16(const u16* g, u16* l) {
  __builtin_amdgcn_global_load_lds((const __attribute__((address_space(1))) void*)g,
                                   (__attribute__((address_space(3))) void*)l, 16, 0, 0);
}

// ---------------- x: fp32 -> bf16 ----------------
__global__ __launch_bounds__(256) void k_cvt_x(const float* __restrict__ x,
                                               u16* __restrict__ xb) {
  const int i = blockIdx.x * 256 + threadIdx.x;
  float4 v = ((const float4*)x)[i];
  ushort4 o;
  o.x = f2bf(v.x); o.y = f2bf(v.y); o.z = f2bf(v.z); o.w = f2bf(v.w);
  ((ushort4*)xb)[i] = o;
}

// ---------------- transpose fp32 -> bf16 (64x64 tile via LDS, XOR-swizzled) ----------------
__device__ __forceinline__ void transpose64f(const float* src, int sstride,
                                             u16* dst, int dstride,
                                             float scale, u16* tile /*64*80*/) {
  const int tid = threadIdx.x;
  const int row = tid >> 3, seg = tid & 7;
#pragma unroll
  for (int p = 0; p < 2; ++p) {
    int rr = p * 32 + row;
    int rw = rr ^ (seg * 8);
    float4 a = *(const float4*)(src + rr * sstride + seg * 8);
    float4 b = *(const float4*)(src + rr * sstride + seg * 8 + 4);
    tile[(seg * 8 + 0) * 80 + rw] = f2bf(a.x * scale);
    tile[(seg * 8 + 1) * 80 + rw] = f2bf(a.y * scale);
    tile[(seg * 8 + 2) * 80 + rw] = f2bf(a.z * scale);
    tile[(seg * 8 + 3) * 80 + rw] = f2bf(a.w * scale);
    tile[(seg * 8 + 4) * 80 + rw] = f2bf(b.x * scale);
    tile[(seg * 8 + 5) * 80 + rw] = f2bf(b.y * scale);
    tile[(seg * 8 + 6) * 80 + rw] = f2bf(b.z * scale);
    tile[(seg * 8 + 7) * 80 + rw] = f2bf(b.w * scale);
  }
  __syncthreads();
#pragma unroll
  for (int p = 0; p < 2; ++p) {
    int rr = p * 32 + row;
    int sw = (seg ^ ((rr >> 3) & 7)) * 8;
    *(uint4*)(dst + rr * dstride + seg * 8) = *(uint4*)(tile + rr * 80 + sw);
  }
}

// ---------------- transpose bf16 -> bf16 (for V), XOR-swizzled ----------------
__device__ __forceinline__ void transpose64(const u16* src, int sstride,
                                            u16* dst, int dstride, u16* tile) {
  const int tid = threadIdx.x;
  const int row = tid >> 3, seg = tid & 7;
  union { uint4 u; u16 s[8]; } tv;
#pragma unroll
  for (int p = 0; p < 2; ++p) {
    int rr = p * 32 + row;
    int rw = rr ^ (seg * 8);
    tv.u = *(const uint4*)(src + rr * sstride + seg * 8);
#pragma unroll
    for (int j = 0; j < 8; ++j)
      tile[(seg * 8 + j) * 80 + rw] = tv.s[j];
  }
  __syncthreads();
#pragma unroll
  for (int p = 0; p < 2; ++p) {
    int rr = p * 32 + row;
    int sw = (seg ^ ((rr >> 3) & 7)) * 8;
    *(uint4*)(dst + rr * dstride + seg * 8) = *(uint4*)(tile + rr * 80 + sw);
  }
}

// Wq|Wk|Wv (each 256x2048 fp32) -> Wt (6144x256 bf16), q/k scaled 0.25
__global__ __launch_bounds__(256) void k_transpose_wqkv(const float* __restrict__ Wq,
                                                        const float* __restrict__ Wk,
                                                        const float* __restrict__ Wv,
                                                        u16* __restrict__ Wt) {
  __shared__ u16 tile[64 * 80];
  const int o0 = blockIdx.x * 64, i0 = blockIdx.y * 64;
  const float* src; float scale = 0.25f; int oc0 = o0;
  if (o0 < 2048)      { src = Wq; }
  else if (o0 < 4096) { src = Wk; oc0 = o0 - 2048; }
  else                { src = Wv; oc0 = o0 - 4096; scale = 1.0f; }
  transpose64f(src + i0 * 2048 + oc0, 2048, Wt + o0 * 256 + i0, 256, scale, tile);
}

// Wu (2048x256 fp32) -> Wut (256x2048 bf16)
__global__ __launch_bounds__(256) void k_transpose_wu(const float* __restrict__ Wu,
                                                      u16* __restrict__ Wut) {
  __shared__ u16 tile[64 * 80];
  const int c0 = blockIdx.x * 64, r0 = blockIdx.y * 64;
  transpose64f(Wu + r0 * 256 + c0, 256, Wut + c0 * 2048 + r0, 2048, 1.0f, tile);
}

// V slice of qkv (b,t,h,d) -> vt (b,h,d,t), bf16
__global__ __launch_bounds__(256) void k_transpose_v(const u16* __restrict__ qkv,
                                                     u16* __restrict__ vt) {
  __shared__ u16 tile[64 * 80];
  const int bh = blockIdx.z;
  const int b = bh >> 3, h = bh & 7;
  const int t0 = blockIdx.y * 64, d0 = blockIdx.x * 64;
  const u16* src = qkv + ((size_t)(b * 1024 + t0)) * 6144 + 4096 + h * 256 + d0;
  u16* dst = vt + ((size_t)(bh * 256 + d0)) * 1024 + t0;
  transpose64(src, 6144, dst, 1024, tile);
}

// ---------------- QKV projection GEMM ----------------
__global__ __launch_bounds__(256) void k_gemm_qkv(const u16* __restrict__ A,
                                                  const u16* __restrict__ Bt,
                                                  u16* __restrict__ C) {
  __shared__ u16 As[128 * 32];
  __shared__ u16 Bs[128 * 32];
  const int m0 = blockIdx.y * 128, n0 = blockIdx.x * 128;
  const int tid = threadIdx.x, w = tid >> 6, lane = tid & 63;
  const int q = lane >> 4, r = lane & 15;
  const int wm = (w >> 1) * 64, wn = (w & 1) * 64;
  const int bo0 = w * 2048 + lane * 16;
  const int row0 = bo0 >> 6, col0 = (bo0 & 63) >> 1;
  const int bo1 = bo0 + 1024;
  const int row1 = bo1 >> 6, col1 = (bo1 & 63) >> 1;
  f32x4 acc[4][4] = {};
  for (int kt = 0; kt < 256; kt += 32) {
    __syncthreads();
    gl_lds16(A + (m0 + row0) * 256 + kt + col0, As + w * 1024);
    gl_lds16(A + (m0 + row1) * 256 + kt + col1, As + w * 1024 + 512);
    gl_lds16(Bt + (n0 + row0) * 256 + kt + col0, Bs + w * 1024);
    gl_lds16(Bt + (n0 + row1) * 256 + kt + col1, Bs + w * 1024 + 512);
    __syncthreads();
    bf16x8 af[4], bf[4];
#pragma unroll
    for (int mb = 0; mb < 4; ++mb) af[mb] = *(const bf16x8*)(As + (wm + mb * 16 + r) * 32 + q * 8);
#pragma unroll
    for (int nb = 0; nb < 4; ++nb) bf[nb] = *(const bf16x8*)(Bs + (wn + nb * 16 + r) * 32 + q * 8);
#pragma unroll
    for (int mb = 0; mb < 4; ++mb)
#pragma unroll
      for (int nb = 0; nb < 4; ++nb)
        acc[mb][nb] = __builtin_amdgcn_mfma_f32_16x16x32_bf16(af[mb], bf[nb], acc[mb][nb], 0, 0, 0);
  }
#pragma unroll
  for (int mb = 0; mb < 4; ++mb)
#pragma unroll
    for (int nb = 0; nb < 4; ++nb) {
      const int nn = n0 + wn + nb * 16 + r;
#pragma unroll
      for (int reg = 0; reg < 4; ++reg) {
        const int mm = m0 + wm + mb * 16 + q * 4 + reg;
        C[(size_t)mm * 6144 + nn] = f2bf(acc[mb][nb][reg]);
      }
    }
}

// ---------------- fused flash attention (S^T / O^T, 32 q-rows/wave, fixed-ref softmax) ---
// Scores are bounded (|s| <~ 30 worst case) -> softmax without max subtraction is safe:
// p = exp(s) in fp32/bf16 (scale-invariant rel. error), normalize by l (fp32) at the end.
// Removes per-chunk: max bookkeeping, reduction shuffles, O-rescale. l is a per-lane
// partial reduced ONCE at the end.
__global__ __launch_bounds__(256, 2) void k_attn(const u16* __restrict__ qkv,
                                                 const u16* __restrict__ vt,
                                                 u16* __restrict__ att) {
  __shared__ u16 smem[17152];   // K frag [0,8192) | V frag [8192,16384) | Os overlay [0,17152)
  const int blk = blockIdx.x;
  const int qt = blk >> 6, bh = blk & 63;       // bh-major: XCD = h -> L2 chunk sharing
  const int b = bh >> 3, h = bh & 7;
  const int tid = threadIdx.x, w = tid >> 6, lane = tid & 63;
  const int q = lane >> 4, r = lane & 15;
  const int t0 = qt * 128 + w * 32;

  // Q B-fragments (two row groups), loaded once
  const u16* QgA = qkv + ((size_t)(b * 1024 + t0 + r)) * 6144 + h * 256;
  const u16* QgB = QgA + (size_t)16 * 6144;
  bf16x8 qfA[8], qfB[8];
#pragma unroll
  for (int kc = 0; kc < 8; ++kc) {
    qfA[kc] = *(const bf16x8*)(QgA + kc * 32 + q * 8);
    qfB[kc] = *(const bf16x8*)(QgB + kc * 32 + q * 8);
  }

  float lA = 0.0f, lB = 0.0f;   // per-lane partial softmax denominators
  f32x4 oA[16] = {}, oB[16] = {};

  const u16* Kg = qkv + (size_t)b * 1024 * 6144 + 2048 + h * 256;
  const u16* Vg = vt + (size_t)(b * 8 + h) * 256 * 1024;

  const int kc_s = (tid & 31) >> 2, kq_s = tid & 3;   // K staging decode
  const int db_s = tid >> 4, vr_s = tid & 15;          // V staging decode

  for (int sc = 0; sc < 1024; sc += 32) {
    __syncthreads();
    // ---- stage K (32 keys x 256 d), fragment-major; rotation (kr+kq+4*kc)&15 keeps both
    // the staging write (kq,kc vary per lane) and the frag read (r varies) conflict-free.
    {
      uint4 kv[4];
#pragma unroll
      for (int p = 0; p < 4; ++p) {
        int key = p * 8 + (tid >> 5);
        kv[p] = *(const uint4*)(Kg + (size_t)(sc + key) * 6144 + (tid & 31) * 8);
      }
#pragma unroll
      for (int p = 0; p < 4; ++p) {
        int key = p * 8 + (tid >> 5);
        int sb = key >> 4, kr = key & 15;
        int unit = (kc_s * 2 + sb) * 64 + kq_s * 16 + ((kr + kq_s + kc_s * 4) & 15);
        *(uint4*)(smem + unit * 8) = kv[p];
      }
    }
    // ---- stage V^T (256 d x 32 keys), fragment-major swizzled
    {
      uint4 vv[4];
#pragma unroll
      for (int p = 0; p < 4; ++p)
        vv[p] = *(const uint4*)(Vg + (size_t)tid * 1024 + sc + p * 8);
#pragma unroll
      for (int p = 0; p < 4; ++p) {
        int unit = db_s * 64 + p * 16 + ((vr_s + p) & 15);
        *(uint4*)(smem + 8192 + unit * 8) = vv[p];
      }
    }
    __syncthreads();

    // ---- S^T = K Q^T for both row groups; each K fragment feeds 2 MFMAs
    f32x4 s0A = {}, s1A = {}, s0B = {}, s1B = {};
#pragma unroll
    for (int kc = 0; kc < 8; ++kc) {
      bf16x8 k0 = *(const bf16x8*)(smem + ((kc * 2 + 0) * 64 + q * 16 + ((r + q + kc * 4) & 15)) * 8);
      bf16x8 k1 = *(const bf16x8*)(smem + ((kc * 2 + 1) * 64 + q * 16 + ((r + q + kc * 4) & 15)) * 8);
      s0A = __builtin_amdgcn_mfma_f32_16x16x32_bf16(k0, qfA[kc], s0A, 0, 0, 0);
      s1A = __builtin_amdgcn_mfma_f32_16x16x32_bf16(k1, qfA[kc], s1A, 0, 0, 0);
      s0B = __builtin_amdgcn_mfma_f32_16x16x32_bf16(k0, qfB[kc], s0B, 0, 0, 0);
      s1B = __builtin_amdgcn_mfma_f32_16x16x32_bf16(k1, qfB[kc], s1B, 0, 0, 0);
    }

    // ---- fixed-reference softmax + P^T fragment via packed shuffles
    union { bf16x8 v; u16 e[8]; } pfA, pfB;
    {
      float pa[4], pb[4];
#pragma unroll
      for (int reg = 0; reg < 4; ++reg) {
        pa[reg] = exp2f(s0A[reg] * LOG2E);
        pb[reg] = exp2f(s1A[reg] * LOG2E);
        lA += pa[reg] + pb[reg];
      }
      uint32_t pk[4];
#pragma unroll
      for (int reg = 0; reg < 4; ++reg)
        pk[reg] = (uint32_t)f2bf(pa[reg]) | ((uint32_t)f2bf(pb[reg]) << 16);
      const int srcA = ((q & 1) << 5) + r, srcB = srcA + 16;
      uint32_t tt[8];
#pragma unroll
      for (int reg = 0; reg < 4; ++reg) tt[reg] = (uint32_t)__shfl((int)pk[reg], srcA);
#pragma unroll
      for (int reg = 0; reg < 4; ++reg) tt[4 + reg] = (uint32_t)__shfl((int)pk[reg], srcB);
      const bool hi = (q >= 2);
#pragma unroll
      for (int j = 0; j < 8; ++j)
        pfA.e[j] = hi ? (u16)(tt[j] >> 16) : (u16)(tt[j] & 0xffffu);
    }
    {
      float pa[4], pb[4];
#pragma unroll
      for (int reg = 0; reg < 4; ++reg) {
        pa[reg] = exp2f(s0B[reg] * LOG2E);
        pb[reg] = exp2f(s1B[reg] * LOG2E);
        lB += pa[reg] + pb[reg];
      }
      uint32_t pk[4];
#pragma unroll
      for (int reg = 0; reg < 4; ++reg)
        pk[reg] = (uint32_t)f2bf(pa[reg]) | ((uint32_t)f2bf(pb[reg]) << 16);
      const int srcA = ((q & 1) << 5) + r, srcB = srcA + 16;
      uint32_t tt[8];
#pragma unroll
      for (int reg = 0; reg < 4; ++reg) tt[reg] = (uint32_t)__shfl((int)pk[reg], srcA);
#pragma unroll
      for (int reg = 0; reg < 4; ++reg) tt[4 + reg] = (uint32_t)__shfl((int)pk[reg], srcB);
      const bool hi = (q >= 2);
#pragma unroll
      for (int j = 0; j < 8; ++j)
        pfB.e[j] = hi ? (u16)(tt[j] >> 16) : (u16)(tt[j] & 0xffffu);
    }

    // ---- O^T += V^T P^T; each V fragment feeds 2 MFMAs
#pragma unroll
    for (int db = 0; db < 16; ++db) {
      bf16x8 vf = *(const bf16x8*)(smem + 8192 + (db * 64 + q * 16 + ((r + q) & 15)) * 8);
      oA[db] = __builtin_amdgcn_mfma_f32_16x16x32_bf16(vf, pfA.v, oA[db], 0, 0, 0);
      oB[db] = __builtin_amdgcn_mfma_f32_16x16x32_bf16(vf, pfB.v, oB[db], 0, 0, 0);
    }
  }

  // ---- final l reduction (once): lanes r, r+16, r+32, r+48 share qrow r
  lA += __shfl_xor(lA, 16); lA += __shfl_xor(lA, 32);
  lB += __shfl_xor(lB, 16); lB += __shfl_xor(lB, 32);
  float rlA = 1.0f / lA, rlB = 1.0f / lB;

  // ---- epilogue: two passes through per-wave Os buffer (16 rows x pitch 268)
  __syncthreads();  // all waves done with K/V region before overlay
  u16* Os = smem + w * 4288;
#pragma unroll
  for (int pass = 0; pass < 2; ++pass) {
    const f32x4* o = pass ? oB : oA;
    const float rl = pass ? rlB : rlA;
    const int tb = t0 + pass * 16;
    __syncthreads();  // prior pass's reads done before overwrite
#pragma unroll
    for (int db = 0; db < 16; ++db) {
      uint32_t lo = (uint32_t)f2bf(o[db][0] * rl) | ((uint32_t)f2bf(o[db][1] * rl) << 16);
      uint32_t hi2 = (uint32_t)f2bf(o[db][2] * rl) | ((uint32_t)f2bf(o[db][3] * rl) << 16);
      uint2 val; val.x = lo; val.y = hi2;
      *(uint2*)(Os + r * 268 + db * 16 + q * 4) = val;
    }
    asm volatile("s_waitcnt lgkmcnt(0)" ::: "memory");
    u16* Ag = att + ((size_t)(b * 1024 + tb)) * 2048 + h * 256;
#pragma unroll
    for (int p = 0; p < 8; ++p) {
      int idx = (p * 64 + lane) * 8;
      int row = idx >> 8, col = idx & 255;
      *(uint4*)(Ag + (size_t)row * 2048 + col) = *(uint4*)(Os + row * 268 + col);
    }
  }
}

// ---------------- unify GEMM + bias ----------------
__global__ __launch_bounds__(256) void k_gemm_out(const u16* __restrict__ A,
                                                  const u16* __restrict__ Bt,
                                                  const float* __restrict__ bu,
                                                  float* __restrict__ C) {
  __shared__ u16 As[128 * 32];
  __shared__ u16 Bs[64 * 32];
  const int m0 = blockIdx.y * 128, n0 = blockIdx.x * 64;
  const int tid = threadIdx.x, w = tid >> 6, lane = tid & 63;
  const int q = lane >> 4, r = lane & 15;
  const int wm = (w >> 1) * 64, wn = (w & 1) * 32;
  const int boA0 = w * 2048 + lane * 16;
  const int rA0 = boA0 >> 6, cA0 = (boA0 & 63) >> 1;
  const int boA1 = boA0 + 1024;
  const int rA1 = boA1 >> 6, cA1 = (boA1 & 63) >> 1;
  const int boB = w * 1024 + lane * 16;
  const int rB = boB >> 6, cB = (boB & 63) >> 1;
  f32x4 acc[4][2] = {};
  for (int kt = 0; kt < 2048; kt += 32) {
    __syncthreads();
    gl_lds16(A + (size_t)(m0 + rA0) * 2048 + kt + cA0, As + w * 1024);
    gl_lds16(A + (size_t)(m0 + rA1) * 2048 + kt + cA1, As + w * 1024 + 512);
    gl_lds16(Bt + (size_t)(n0 + rB) * 2048 + kt + cB, Bs + w * 512);
    __syncthreads();
    bf16x8 af[4], bf[2];
#pragma unroll
    for (int mb = 0; mb < 4; ++mb) af[mb] = *(const bf16x8*)(As + (wm + mb * 16 + r) * 32 + q * 8);
#pragma unroll
    for (int nb = 0; nb < 2; ++nb) bf[nb] = *(const bf16x8*)(Bs + (wn + nb * 16 + r) * 32 + q * 8);
#pragma unroll
    for (int mb = 0; mb < 4; ++mb)
#pragma unroll
      for (int nb = 0; nb < 2; ++nb)
        acc[mb][nb] = __builtin_amdgcn_mfma_f32_16x16x32_bf16(af[mb], bf[nb], acc[mb][nb], 0, 0, 0);
  }
  float bias[2];
#pragma unroll
  for (int nb = 0; nb < 2; ++nb) bias[nb] = bu[n0 + wn + nb * 16 + r];
#pragma unroll
  for (int mb = 0; mb < 4; ++mb)
#pragma unroll
    for (int nb = 0; nb < 2; ++nb) {
      const int nn = n0 + wn + nb * 16 + r;
#pragma unroll
      for (int reg = 0; reg < 4; ++reg) {
        const int mm = m0 + wm + mb * 16 + q * 4 + reg;
        C[(size_t)mm * 256 + nn] = acc[mb][nb][reg] + bias[nb];
      }
    }
}

extern "C" void kernel_launch(void* const* d_in, const int* in_sizes, int n_in,
                              void* d_out, int out_size, void* d_ws, size_t ws_size,
                              hipStream_t stream) {
  const float* x  = (const float*)d_in[0];
  const float* Wq = (const float*)d_in[1];
  const float* Wk = (const float*)d_in[2];
  const float* Wv = (const float*)d_in[3];
  const float* Wu = (const float*)d_in[4];
  const float* bu = (const float*)d_in[5];
  float* outp = (float*)d_out;

  char* ws = (char*)d_ws;
  u16* qkv   = (u16*)(ws);                          // 100663296
  u16* vt    = (u16*)(ws + 100663296);              // 33554432
  u16* attb  = (u16*)(ws + 134217728);              // 33554432
  u16* wqkvt = (u16*)(ws + 167772160);              // 3145728
  u16* wut   = (u16*)(ws + 170917888);              // 1048576
  u16* xb    = (u16*)(ws + 171966464);              // 4194304
  (void)in_sizes; (void)n_in; (void)out_size; (void)ws_size;

  dim3 blk(256);
  k_cvt_x<<<dim3(2048), blk, 0, stream>>>(x, xb);
  k_transpose_wqkv<<<dim3(96, 4), blk, 0, stream>>>(Wq, Wk, Wv, wqkvt);
  k_transpose_wu<<<dim3(4, 32), blk, 0, stream>>>(Wu, wut);
  k_gemm_qkv<<<dim3(48, 64), blk, 0, stream>>>(xb, wqkvt, qkv);
  k_transpose_v<<<dim3(4, 16, 64), blk, 0, stream>>>(qkv, vt);
  k_attn<<<dim3(512), blk, 0, stream>>>(qkv, vt, attb);
  k_gemm_out<<<dim3(4, 64), blk, 0, stream>>>(attb, wut, bu, outp);
}